// Round 7
// baseline (175.516 us; speedup 1.0000x reference)
//
#include <hip/hip_runtime.h>
#include <stdint.h>

typedef unsigned short u16;
typedef __attribute__((ext_vector_type(8))) short bf16x8;
typedef __attribute__((ext_vector_type(4))) float f32x4;

typedef __attribute__((address_space(3))) uint32_t lds_u32_t;
typedef const __attribute__((address_space(1))) uint32_t glb_u32_t;

__device__ __forceinline__ void glds16(const void* g, void* l){
  __builtin_amdgcn_global_load_lds((glb_u32_t*)g, (lds_u32_t*)l, 16, 0, 0);
}

__device__ __forceinline__ u16 f2bf(float f){
  union { float f; uint32_t u; } v; v.f = f;
  uint32_t u = v.u;
  u += 0x7FFFu + ((u >> 16) & 1u);
  return (u16)(u >> 16);
}

__device__ __forceinline__ float fexp2(float x){
#if __has_builtin(__builtin_amdgcn_exp2f)
  return __builtin_amdgcn_exp2f(x);
#else
  return exp2f(x);
#endif
}

__device__ __forceinline__ uint32_t cvtpk_bf16(float lo, float hi){
  uint32_t d;
  asm("v_cvt_pk_bf16_f32 %0, %1, %2" : "=v"(d) : "v"(lo), "v"(hi));
  return d;
}

__device__ __forceinline__ f32x4 mfma_bf16(bf16x8 a, bf16x8 b, f32x4 c){
  return __builtin_amdgcn_mfma_f32_16x16x32_bf16(a, b, c, 0, 0, 0);
}

// 0.125 (1/sqrt(64)) * log2(e) -- folded into Q at the QKV epilogue
#define QSCALE 0.1803368801111244f

// ---------------- cast x (fp32 -> bf16), 4 elems/thread ----------------
__global__ __launch_bounds__(256) void cast_x_k(const float* __restrict__ x,
                                                u16* __restrict__ xb, int n4){
  int i = blockIdx.x*256 + threadIdx.x;
  if (i >= n4) return;
  float4 v = reinterpret_cast<const float4*>(x)[i];
  uint2 o;
  o.x = (uint32_t)f2bf(v.x) | ((uint32_t)f2bf(v.y) << 16);
  o.y = (uint32_t)f2bf(v.z) | ((uint32_t)f2bf(v.w) << 16);
  reinterpret_cast<uint2*>(xb)[i] = o;
}

// ---------------- transpose+cast: fp32 [R][C] -> bf16 [C][R] ----------------
__global__ __launch_bounds__(256) void transpose_cast_k(const float* __restrict__ in,
                                                        u16* __restrict__ out,
                                                        int R, int C){
  __shared__ u16 tile[64][66];
  int c0 = blockIdx.x*64, r0 = blockIdx.y*64;
  int tc = threadIdx.x & 63, t4 = threadIdx.x >> 6;
  #pragma unroll
  for (int i=0;i<16;i++){ int r = t4 + i*4; tile[r][tc] = f2bf(in[(size_t)(r0+r)*C + c0 + tc]); }
  __syncthreads();
  #pragma unroll
  for (int i=0;i<16;i++){ int cc = t4 + i*4; out[(size_t)(c0+cc)*R + r0 + tc] = tile[tc][cc]; }
}

// ---------------- bf16 MFMA GEMM (m97-style global_load_lds staging) ----------------
// C[M][N] = A[M][K] * Bt[N][K]^T + bias
// Staging per k-step: 8KB per operand = 8 chunks of 1KB. Chunk c = wid*2+s:
// LDS dest is the WAVE-UNIFORM base &As[c*512] (HW semantics: lane i lands at
// base + i*16 bytes); the GLOBAL src is lane-mapped to match that layout:
// row = c*16 + (lane>>2), col = (lane&3)*8  -> linear row-major [128][32].
// mode 0: fp32 out to fo.
// mode 1: scatter bf16: q (pre-scaled) and k into [B*H][T][64]; v written TRANSPOSED
//         into [B*H][64][T].
__global__ __launch_bounds__(256) void gemm_bf16_k(
    const u16* __restrict__ A, const u16* __restrict__ Bt,
    int M, int N, int K, const float* __restrict__ bias, int mode,
    u16* __restrict__ qo, u16* __restrict__ ko, u16* __restrict__ vo,
    float* __restrict__ fo)
{
  __shared__ u16 As[128*32];   // linear (global_load_lds writes base + lane*16)
  __shared__ u16 Bs[128*32];
  const int m0 = blockIdx.y*128, n0 = blockIdx.x*128;
  const int tid = threadIdx.x, lane = tid & 63, wid = tid >> 6;
  const int lr = lane & 15, lg = lane >> 4;
  const int wr = wid >> 1, wc = wid & 1;
  const int srow = lane >> 2, scol = (lane & 3)*8;   // staging lane map
  f32x4 acc[4][4] = {};
  const int nk = K >> 5;
  for (int kk = 0; kk < nk; ++kk){
    #pragma unroll
    for (int s = 0; s < 2; ++s){
      int c = wid*2 + s;                 // chunk 0..7 (16 rows each)
      int row = c*16 + srow;
      glds16(&A[(size_t)(m0+row)*K + kk*32 + scol], &As[c*512]);
      glds16(&Bt[(size_t)(n0+row)*K + kk*32 + scol], &Bs[c*512]);
    }
    __syncthreads();   // compiler drains vmcnt before barrier
    bf16x8 af[4], bfr[4];
    #pragma unroll
    for (int m=0;m<4;m++) af[m] = *(const bf16x8*)&As[(wr*64 + m*16 + lr)*32 + lg*8];
    #pragma unroll
    for (int n=0;n<4;n++) bfr[n] = *(const bf16x8*)&Bs[(wc*64 + n*16 + lr)*32 + lg*8];
    #pragma unroll
    for (int m=0;m<4;m++)
      #pragma unroll
      for (int n=0;n<4;n++)
        acc[m][n] = mfma_bf16(af[m], bfr[n], acc[m][n]);
    __syncthreads();
  }
  if (mode == 0){
    #pragma unroll
    for (int m=0;m<4;m++)
      #pragma unroll
      for (int n=0;n<4;n++){
        int gn = n0 + wc*64 + n*16 + lr;
        float bv = bias[gn];
        #pragma unroll
        for (int r=0;r<4;r++){
          int gm = m0 + wr*64 + m*16 + lg*4 + r;
          fo[(size_t)gm*N + gn] = acc[m][n][r] + bv;
        }
      }
  } else {
    int which = n0 / 768;               // 0=q 1=k 2=v, uniform per block
    u16* dst = (which==0) ? qo : ko;
    float sc = (which==0) ? QSCALE : 1.0f;
    #pragma unroll
    for (int m=0;m<4;m++)
      #pragma unroll
      for (int n=0;n<4;n++){
        int gn = n0 + wc*64 + n*16 + lr;
        float bv = bias[gn];
        int cn = gn - which*768;
        int h = cn >> 6, d = cn & 63;
        int gm0 = m0 + wr*64 + m*16 + lg*4;
        int b = gm0 >> 11, t0 = gm0 & 2047;
        if (which < 2){
          #pragma unroll
          for (int r=0;r<4;r++)
            dst[(size_t)((b*12 + h)*2048 + t0 + r)*64 + d] = f2bf((acc[m][n][r] + bv)*sc);
        } else {
          uint2 o;
          o.x = cvtpk_bf16(acc[m][n][0]+bv, acc[m][n][1]+bv);
          o.y = cvtpk_bf16(acc[m][n][2]+bv, acc[m][n][3]+bv);
          *(uint2*)&vo[((size_t)((b*12 + h)*64 + d))*2048 + t0] = o;
        }
      }
  }
}

// ---------------- causal flash attention: split-K, XCD-pinned, burst loads ----------
// 1-D grid of 3072 blocks: head = i % 24 (pinned to XCD h%8 since 24 == 0 mod 8,
// 3 heads/XCD -> K/V L2-resident), qt = 127 - i/24 (global heavy-first).
// Block = 256 thr = one 16-row q-tile; wave w handles key-tiles t = w, w+4, ...
// SINGLE-buffered K+V: all 16 fragment loads issue as one dependence-free burst at
// the loop top (one exposed L2 latency per tile, not 30); u32 offsets bumped by a
// constant. __launch_bounds__(256,3) keeps 3 waves/SIMD resident.
// Swapped QK^T (mfma(K,Q)); FIXED shift m2=8 => exp2 straight off the MFMA; overflow
// guard off-chain, rare fixup rescales after PV (exact). One-barrier merge.
__global__ __launch_bounds__(256, 3) void attn_k(
    const u16* __restrict__ qp, const u16* __restrict__ kp,
    const u16* __restrict__ vtp, u16* __restrict__ yp)
{
  __shared__ f32x4 yl[16][64];        // [w*4+n][lane]
  __shared__ float ml[4][16];
  __shared__ float ll[4][16];
  const int i = blockIdx.x;
  const int bh = i % 24;
  const int qt = 127 - (i / 24);            // heavy first, all heads at once
  const int q0w = qt * 16;
  const int b = bh / 12, h = bh - b*12;
  const size_t base = (size_t)bh * 131072;  // 2048*64
  const int tid = threadIdx.x, lane = tid & 63, wid = tid >> 6;
  const int lr = lane & 15, lg = lane >> 4;
  const int qg = q0w + lr;
  const char* kbase = (const char*)(kp + base);
  const char* vbase = (const char*)(vtp + base);

  bf16x8 qf[2];
  #pragma unroll
  for (int kb=0;kb<2;kb++)
    qf[kb] = *(const bf16x8*)&qp[base + (size_t)qg*64 + kb*32 + lg*8];

  f32x4 yacc[4] = {};
  float m2 = 8.f, l = 0.f;
  const int nt = (qt >> 2) + 1;

  // u32 byte offsets for this wave's first tile (t = wid); bumped by consts per iter
  uint32_t ko[8], vo[8];
  #pragma unroll
  for (int nb=0;nb<4;nb++){
    int ke = ((nb&1)*32 + (lr>>2)*8 + (nb>>1)*4 + (lr&3))*64 + lg*8;  // pi-permuted
    ko[nb*2+0] = (uint32_t)(wid*4096 + ke) * 2u;
    ko[nb*2+1] = (uint32_t)(wid*4096 + ke + 32) * 2u;
  }
  #pragma unroll
  for (int n=0;n<4;n++){
    int ve = (n*16+lr)*2048 + lg*8 + wid*64;
    vo[n*2+0] = (uint32_t)ve * 2u;
    vo[n*2+1] = (uint32_t)(ve + 32) * 2u;
  }

  for (int t = wid; t < nt; t += 4){
    // ---- dependence-free 16-load burst (one exposed latency) ----
    bf16x8 kf[8], vf[8];
    #pragma unroll
    for (int j=0;j<8;j++) kf[j] = *(const bf16x8*)(kbase + ko[j]);
    #pragma unroll
    for (int j=0;j<8;j++) vf[j] = *(const bf16x8*)(vbase + vo[j]);
    #pragma unroll
    for (int j=0;j<8;j++){ ko[j] += 32768u; vo[j] += 512u; }

    const int k0 = t*64;
    const int nbmin[4] = {0, 32, 4, 36};
    f32x4 s[4] = {};
    __builtin_amdgcn_s_setprio(1);
    #pragma unroll
    for (int nb=0;nb<4;nb++){
      if (k0 + nbmin[nb] <= q0w + 15){
        s[nb] = mfma_bf16(kf[nb*2+0], qf[0], s[nb]);
        s[nb] = mfma_bf16(kf[nb*2+1], qf[1], s[nb]);
      }
    }
    __builtin_amdgcn_s_setprio(0);
    if (k0 + 63 > q0w){                    // diagonal tile only: causal mask
      #pragma unroll
      for (int nb=0;nb<4;nb++){
        int kb0 = k0 + (nb&1)*32 + ((nb>>1)&1)*4 + lg*8;
        #pragma unroll
        for (int r=0;r<4;r++)
          if (kb0 + r > qg) s[nb][r] = -1e30f;
      }
    }
    // p = 2^(s - m2) straight off the MFMA output
    float lsum = 0.f;
    #pragma unroll
    for (int nb=0;nb<4;nb++){
      if (k0 + nbmin[nb] <= q0w + 15){
        #pragma unroll
        for (int r=0;r<4;r++){
          float p = fexp2(s[nb][r] - m2);
          s[nb][r] = p;
          lsum += p;
        }
      } else {
        #pragma unroll
        for (int r=0;r<4;r++) s[nb][r] = 0.f;
      }
    }
    // pack + PV (critical chain)
    uint32_t pk8[8];
    #pragma unroll
    for (int nb=0;nb<4;nb++){
      pk8[nb*2]   = cvtpk_bf16(s[nb][0], s[nb][1]);
      pk8[nb*2+1] = cvtpk_bf16(s[nb][2], s[nb][3]);
    }
    __builtin_amdgcn_s_setprio(1);
    #pragma unroll
    for (int kc=0;kc<2;kc++){
      union { uint32_t u[4]; bf16x8 v; } pb;
      pb.u[0] = pk8[kc*2];   pb.u[1] = pk8[kc*2+1];
      pb.u[2] = pk8[kc*2+4]; pb.u[3] = pk8[kc*2+5];
      #pragma unroll
      for (int n=0;n<4;n++)
        yacc[n] = mfma_bf16(vf[n*2+kc], pb.v, yacc[n]);
    }
    __builtin_amdgcn_s_setprio(0);
    l += lsum;
    // off-chain overflow guard: threshold 2^11.5; fixup AFTER PV (exact)
    float pmax = s[0][0];
    #pragma unroll
    for (int nb=0;nb<4;nb++){
      #pragma unroll
      for (int r=0;r<4;r++) pmax = fmaxf(pmax, s[nb][r]);
    }
    pmax = fmaxf(pmax, __shfl_xor(pmax, 16));
    pmax = fmaxf(pmax, __shfl_xor(pmax, 32));
    if (!__all(pmax <= 2896.31f)){
      float m2n = fmaxf(m2, m2 + __log2f(pmax));
      float al = fexp2(m2 - m2n);
      l *= al;
      #pragma unroll
      for (int n=0;n<4;n++) yacc[n] *= al;
      m2 = m2n;
    }
  }

  // per-wave l: sum across the 4 lg-lanes of each q-row
  l += __shfl_xor(l, 16);
  l += __shfl_xor(l, 32);

  // publish partials
  #pragma unroll
  for (int n=0;n<4;n++) yl[wid*4+n][lane] = yacc[n];
  if (lg == 0){ ml[wid][lr] = m2; ll[wid][lr] = l; }
  __syncthreads();

  // merge: wave `wid` produces output slice n = wid
  float m0 = ml[0][lr], m1 = ml[1][lr], m2r = ml[2][lr], m3 = ml[3][lr];
  float ms = fmaxf(fmaxf(m0, m1), fmaxf(m2r, m3));
  float a0 = fexp2(m0 - ms), a1 = fexp2(m1 - ms),
        a2 = fexp2(m2r - ms), a3 = fexp2(m3 - ms);
  float Ls = a0*ll[0][lr] + a1*ll[1][lr] + a2*ll[2][lr] + a3*ll[3][lr];
  f32x4 y0 = yl[0*4+wid][lane], y1 = yl[1*4+wid][lane],
        y2 = yl[2*4+wid][lane], y3 = yl[3*4+wid][lane];
  f32x4 ys;
  #pragma unroll
  for (int r=0;r<4;r++) ys[r] = a0*y0[r] + a1*y1[r] + a2*y2[r] + a3*y3[r];
  float inv = 1.0f / Ls;
  uint2 o;
  o.x = cvtpk_bf16(ys[0]*inv, ys[1]*inv);
  o.y = cvtpk_bf16(ys[2]*inv, ys[3]*inv);
  *(uint2*)&yp[(size_t)(b*2048 + qg)*768 + h*64 + wid*16 + lg*4] = o;
}

extern "C" void kernel_launch(void* const* d_in, const int* in_sizes, int n_in,
                              void* d_out, int out_size, void* d_ws, size_t ws_size,
                              hipStream_t stream)
{
  const float* x  = (const float*)d_in[0];   // [2,2048,768]
  const float* Wa = (const float*)d_in[1];   // [768,2304]
  const float* ba = (const float*)d_in[2];   // [2304]
  const float* Wp = (const float*)d_in[3];   // [768,768]
  const float* bp = (const float*)d_in[4];   // [768]
  float* out = (float*)d_out;                // [2,2048,768] fp32
  char* ws = (char*)d_ws;
  u16* xb  = (u16*)(ws + 0);         // x bf16          [4096][768]
  u16* wt  = (u16*)(ws + 6291456);   // W_attn^T bf16   [2304][768]
  u16* wpt = (u16*)(ws + 9830400);   // W_proj^T bf16   [768][768]
  u16* qb  = (u16*)(ws + 11010048);  // q bf16 (scaled) [24][2048][64]
  u16* kb  = (u16*)(ws + 17301504);  // k bf16          [24][2048][64]
  u16* vtb = (u16*)(ws + 23592960);  // v^T bf16        [24][64][2048]
  u16* yb  = (u16*)(ws + 29884416);  // attn out bf16   [4096][768]

  cast_x_k<<<3072, 256, 0, stream>>>(x, xb, 786432);
  transpose_cast_k<<<dim3(36,12), 256, 0, stream>>>(Wa, wt, 768, 2304);
  transpose_cast_k<<<dim3(12,12), 256, 0, stream>>>(Wp, wpt, 768, 768);
  gemm_bf16_k<<<dim3(18,32), 256, 0, stream>>>(xb, wt, 4096, 2304, 768, ba, 1,
                                               qb, kb, vtb, nullptr);
  attn_k<<<3072, 256, 0, stream>>>(qb, kb, vtb, yb);
  gemm_bf16_k<<<dim3(6,32), 256, 0, stream>>>(yb, wpt, 4096, 768, 768, bp, 0,
                                              nullptr, nullptr, nullptr, out);
}

// Round 8
// 164.129 us; speedup vs baseline: 1.0694x; 1.0694x over previous
//
#include <hip/hip_runtime.h>
#include <stdint.h>

typedef unsigned short u16;
typedef __attribute__((ext_vector_type(8))) short bf16x8;
typedef __attribute__((ext_vector_type(4))) float f32x4;

__device__ __forceinline__ u16 f2bf(float f){
  union { float f; uint32_t u; } v; v.f = f;
  uint32_t u = v.u;
  u += 0x7FFFu + ((u >> 16) & 1u);
  return (u16)(u >> 16);
}

__device__ __forceinline__ float fexp2(float x){
#if __has_builtin(__builtin_amdgcn_exp2f)
  return __builtin_amdgcn_exp2f(x);
#else
  return exp2f(x);
#endif
}

__device__ __forceinline__ uint32_t cvtpk_bf16(float lo, float hi){
  uint32_t d;
  asm("v_cvt_pk_bf16_f32 %0, %1, %2" : "=v"(d) : "v"(lo), "v"(hi));
  return d;
}

__device__ __forceinline__ f32x4 mfma_bf16(bf16x8 a, bf16x8 b, f32x4 c){
  return __builtin_amdgcn_mfma_f32_16x16x32_bf16(a, b, c, 0, 0, 0);
}

// burst load: dwordx4 from SGPR base + 32-bit voffset (+imm). "=&v" early-clobber
// keeps all burst results simultaneously live -- the allocator cannot serialize.
#define GLOADX4(dst, off, sbase)                                            \
  asm volatile("global_load_dwordx4 %0, %1, %2"                             \
               : "=&v"(dst) : "v"(off), "s"(sbase))
#define GLOADX4_O64(dst, off, sbase)                                        \
  asm volatile("global_load_dwordx4 %0, %1, %2 offset:64"                   \
               : "=&v"(dst) : "v"(off), "s"(sbase))

// 0.125 (1/sqrt(64)) * log2(e) -- folded into Q at the QKV epilogue
#define QSCALE 0.1803368801111244f

// ---------------- cast x (fp32 -> bf16), 4 elems/thread ----------------
__global__ __launch_bounds__(256) void cast_x_k(const float* __restrict__ x,
                                                u16* __restrict__ xb, int n4){
  int i = blockIdx.x*256 + threadIdx.x;
  if (i >= n4) return;
  float4 v = reinterpret_cast<const float4*>(x)[i];
  uint2 o;
  o.x = (uint32_t)f2bf(v.x) | ((uint32_t)f2bf(v.y) << 16);
  o.y = (uint32_t)f2bf(v.z) | ((uint32_t)f2bf(v.w) << 16);
  reinterpret_cast<uint2*>(xb)[i] = o;
}

// ---------------- transpose+cast: fp32 [R][C] -> bf16 [C][R] ----------------
__global__ __launch_bounds__(256) void transpose_cast_k(const float* __restrict__ in,
                                                        u16* __restrict__ out,
                                                        int R, int C){
  __shared__ u16 tile[64][66];
  int c0 = blockIdx.x*64, r0 = blockIdx.y*64;
  int tc = threadIdx.x & 63, t4 = threadIdx.x >> 6;
  #pragma unroll
  for (int i=0;i<16;i++){ int r = t4 + i*4; tile[r][tc] = f2bf(in[(size_t)(r0+r)*C + c0 + tc]); }
  __syncthreads();
  #pragma unroll
  for (int i=0;i<16;i++){ int cc = t4 + i*4; out[(size_t)(c0+cc)*R + r0 + tc] = tile[tc][cc]; }
}

// ---------------- bf16 MFMA GEMM: C[M][N] = A[M][K] * Bt[N][K]^T + bias ----------------
// (R5 reg-staged version -- measured faster than glds staging at these shapes)
// mode 0: fp32 out to fo.
// mode 1: scatter bf16: q (pre-scaled) and k into [B*H][T][64]; v written TRANSPOSED
//         into [B*H][64][T].
#define LDP 40   // padded LDS row stride (shorts)

__global__ __launch_bounds__(256) void gemm_bf16_k(
    const u16* __restrict__ A, const u16* __restrict__ Bt,
    int M, int N, int K, const float* __restrict__ bias, int mode,
    u16* __restrict__ qo, u16* __restrict__ ko, u16* __restrict__ vo,
    float* __restrict__ fo)
{
  __shared__ u16 As[128*LDP];
  __shared__ u16 Bs[128*LDP];
  const int m0 = blockIdx.y*128, n0 = blockIdx.x*128;
  const int tid = threadIdx.x, lane = tid & 63, wid = tid >> 6;
  const int lr = lane & 15, lg = lane >> 4;
  const int wr = wid >> 1, wc = wid & 1;
  f32x4 acc[4][4] = {};
  const int nk = K >> 5;
  for (int kk = 0; kk < nk; ++kk){
    #pragma unroll
    for (int s = 0; s < 2; ++s){
      int ci = tid + 256*s;
      int row = ci >> 2, ch = ci & 3;
      *(uint4*)&As[row*LDP + ch*8] = *(const uint4*)&A[(size_t)(m0+row)*K + kk*32 + ch*8];
      *(uint4*)&Bs[row*LDP + ch*8] = *(const uint4*)&Bt[(size_t)(n0+row)*K + kk*32 + ch*8];
    }
    __syncthreads();
    bf16x8 af[4], bfr[4];
    #pragma unroll
    for (int m=0;m<4;m++) af[m] = *(const bf16x8*)&As[(wr*64 + m*16 + lr)*LDP + lg*8];
    #pragma unroll
    for (int n=0;n<4;n++) bfr[n] = *(const bf16x8*)&Bs[(wc*64 + n*16 + lr)*LDP + lg*8];
    #pragma unroll
    for (int m=0;m<4;m++)
      #pragma unroll
      for (int n=0;n<4;n++)
        acc[m][n] = mfma_bf16(af[m], bfr[n], acc[m][n]);
    __syncthreads();
  }
  if (mode == 0){
    #pragma unroll
    for (int m=0;m<4;m++)
      #pragma unroll
      for (int n=0;n<4;n++){
        int gn = n0 + wc*64 + n*16 + lr;
        float bv = bias[gn];
        #pragma unroll
        for (int r=0;r<4;r++){
          int gm = m0 + wr*64 + m*16 + lg*4 + r;
          fo[(size_t)gm*N + gn] = acc[m][n][r] + bv;
        }
      }
  } else {
    int which = n0 / 768;               // 0=q 1=k 2=v, uniform per block
    u16* dst = (which==0) ? qo : ko;
    float sc = (which==0) ? QSCALE : 1.0f;
    #pragma unroll
    for (int m=0;m<4;m++)
      #pragma unroll
      for (int n=0;n<4;n++){
        int gn = n0 + wc*64 + n*16 + lr;
        float bv = bias[gn];
        int cn = gn - which*768;
        int h = cn >> 6, d = cn & 63;
        int gm0 = m0 + wr*64 + m*16 + lg*4;
        int b = gm0 >> 11, t0 = gm0 & 2047;
        if (which < 2){
          #pragma unroll
          for (int r=0;r<4;r++)
            dst[(size_t)((b*12 + h)*2048 + t0 + r)*64 + d] = f2bf((acc[m][n][r] + bv)*sc);
        } else {
          uint2 o;
          o.x = cvtpk_bf16(acc[m][n][0]+bv, acc[m][n][1]+bv);
          o.y = cvtpk_bf16(acc[m][n][2]+bv, acc[m][n][3]+bv);
          *(uint2*)&vo[((size_t)((b*12 + h)*64 + d))*2048 + t0] = o;
        }
      }
  }
}

// ---------------- causal flash attention: split-K, XCD-pinned, asm burst ----------
// 1-D grid of 3072 blocks: head = i % 24 (pinned to XCD h%8), qt = 127 - i/24
// (global heavy-first). Block = 256 thr = one 16-row q-tile; wave w: tiles w, w+4...
// Burst of 16 inline-asm global_load_dwordx4 (K then V) with "=&v" outputs -> all
// results forced simultaneously live, compiler cannot serialize. Counted waits:
// vmcnt(8) before QK^T (K done, V in flight under QK+softmax), vmcnt(0) before PV.
// sched_barrier(0) after each waitcnt (hipcc hoists reg-only MFMA past asm waits).
// Swapped QK^T (mfma(K,Q)); FIXED shift m2=8; overflow fixup after PV (exact).
__global__ __launch_bounds__(256) void attn_k(
    const u16* __restrict__ qp, const u16* __restrict__ kp,
    const u16* __restrict__ vtp, u16* __restrict__ yp)
{
  __shared__ f32x4 yl[16][64];        // [w*4+n][lane]
  __shared__ float ml[4][16];
  __shared__ float ll[4][16];
  const int i = blockIdx.x;
  const int bh = i % 24;
  const int qt = 127 - (i / 24);            // heavy first, all heads at once
  const int q0w = qt * 16;
  const int b = bh / 12, h = bh - b*12;
  const size_t base = (size_t)bh * 131072;  // 2048*64
  const int tid = threadIdx.x, lane = tid & 63, wid = tid >> 6;
  const int lr = lane & 15, lg = lane >> 4;
  const int qg = q0w + lr;
  const u16* kbase = kp + base;
  const u16* vbase = vtp + base;

  bf16x8 qf[2];
  #pragma unroll
  for (int kb=0;kb<2;kb++)
    qf[kb] = *(const bf16x8*)&qp[base + (size_t)qg*64 + kb*32 + lg*8];

  f32x4 yacc[4] = {};
  float m2 = 8.f, l = 0.f;
  const int nt = (qt >> 2) + 1;

  // 32-bit byte voffsets for this wave's first tile (t = wid); bumped per iter
  uint32_t ka0, ka1, ka2, ka3, va0, va1, va2, va3;
  {
    int p0 = ((0)*32 + (lr>>2)*8 + (0)*4 + (lr&3))*64 + lg*8;   // nb=0 pi-perm
    int p1 = ((1)*32 + (lr>>2)*8 + (0)*4 + (lr&3))*64 + lg*8;   // nb=1
    int p2 = ((0)*32 + (lr>>2)*8 + (1)*4 + (lr&3))*64 + lg*8;   // nb=2
    int p3 = ((1)*32 + (lr>>2)*8 + (1)*4 + (lr&3))*64 + lg*8;   // nb=3
    ka0 = (uint32_t)(wid*4096 + p0)*2u;  ka1 = (uint32_t)(wid*4096 + p1)*2u;
    ka2 = (uint32_t)(wid*4096 + p2)*2u;  ka3 = (uint32_t)(wid*4096 + p3)*2u;
    va0 = (uint32_t)((0*16+lr)*2048 + lg*8 + wid*64)*2u;
    va1 = (uint32_t)((1*16+lr)*2048 + lg*8 + wid*64)*2u;
    va2 = (uint32_t)((2*16+lr)*2048 + lg*8 + wid*64)*2u;
    va3 = (uint32_t)((3*16+lr)*2048 + lg*8 + wid*64)*2u;
  }

  for (int t = wid; t < nt; t += 4){
    // ---- 16-load asm burst: K (8) then V (8); second halves via offset:64 ----
    bf16x8 kf0,kf1,kf2,kf3,kf4,kf5,kf6,kf7, vf0,vf1,vf2,vf3,vf4,vf5,vf6,vf7;
    GLOADX4    (kf0, ka0, kbase);  GLOADX4_O64(kf1, ka0, kbase);
    GLOADX4    (kf2, ka1, kbase);  GLOADX4_O64(kf3, ka1, kbase);
    GLOADX4    (kf4, ka2, kbase);  GLOADX4_O64(kf5, ka2, kbase);
    GLOADX4    (kf6, ka3, kbase);  GLOADX4_O64(kf7, ka3, kbase);
    GLOADX4    (vf0, va0, vbase);  GLOADX4_O64(vf1, va0, vbase);
    GLOADX4    (vf2, va1, vbase);  GLOADX4_O64(vf3, va1, vbase);
    GLOADX4    (vf4, va2, vbase);  GLOADX4_O64(vf5, va2, vbase);
    GLOADX4    (vf6, va3, vbase);  GLOADX4_O64(vf7, va3, vbase);
    // bump (executes while loads are in flight)
    ka0 += 32768u; ka1 += 32768u; ka2 += 32768u; ka3 += 32768u;
    va0 += 512u;   va1 += 512u;   va2 += 512u;   va3 += 512u;

    const int k0 = t*64;

    // ---- wait K only (V keeps flying), then QK^T ----
    asm volatile("s_waitcnt vmcnt(8)" ::: "memory");
    __builtin_amdgcn_sched_barrier(0);
    f32x4 s[4] = {};
    __builtin_amdgcn_s_setprio(1);
    if (k0      <= q0w + 15){ s[0]=mfma_bf16(kf0,qf[0],s[0]); s[0]=mfma_bf16(kf1,qf[1],s[0]); }
    if (k0 + 32 <= q0w + 15){ s[1]=mfma_bf16(kf2,qf[0],s[1]); s[1]=mfma_bf16(kf3,qf[1],s[1]); }
    if (k0 +  4 <= q0w + 15){ s[2]=mfma_bf16(kf4,qf[0],s[2]); s[2]=mfma_bf16(kf5,qf[1],s[2]); }
    if (k0 + 36 <= q0w + 15){ s[3]=mfma_bf16(kf6,qf[0],s[3]); s[3]=mfma_bf16(kf7,qf[1],s[3]); }
    __builtin_amdgcn_s_setprio(0);

    if (k0 + 63 > q0w){                    // diagonal tile only: causal mask
      #pragma unroll
      for (int nb=0;nb<4;nb++){
        int kb0 = k0 + (nb&1)*32 + ((nb>>1)&1)*4 + lg*8;
        #pragma unroll
        for (int r=0;r<4;r++)
          if (kb0 + r > qg) s[nb][r] = -1e30f;
      }
    }
    // p = 2^(s - m2) straight off the MFMA output
    const int nbmin[4] = {0, 32, 4, 36};
    float lsum = 0.f;
    #pragma unroll
    for (int nb=0;nb<4;nb++){
      if (k0 + nbmin[nb] <= q0w + 15){
        #pragma unroll
        for (int r=0;r<4;r++){
          float p = fexp2(s[nb][r] - m2);
          s[nb][r] = p;
          lsum += p;
        }
      } else {
        #pragma unroll
        for (int r=0;r<4;r++) s[nb][r] = 0.f;
      }
    }
    // pack P to bf16 in-register
    uint32_t pk8[8];
    #pragma unroll
    for (int nb=0;nb<4;nb++){
      pk8[nb*2]   = cvtpk_bf16(s[nb][0], s[nb][1]);
      pk8[nb*2+1] = cvtpk_bf16(s[nb][2], s[nb][3]);
    }
    // ---- wait V, then PV ----
    asm volatile("s_waitcnt vmcnt(0)" ::: "memory");
    __builtin_amdgcn_sched_barrier(0);
    __builtin_amdgcn_s_setprio(1);
    {
      union { uint32_t u[4]; bf16x8 v; } pb;
      pb.u[0] = pk8[0]; pb.u[1] = pk8[1]; pb.u[2] = pk8[4]; pb.u[3] = pk8[5];
      yacc[0] = mfma_bf16(vf0, pb.v, yacc[0]);
      yacc[1] = mfma_bf16(vf2, pb.v, yacc[1]);
      yacc[2] = mfma_bf16(vf4, pb.v, yacc[2]);
      yacc[3] = mfma_bf16(vf6, pb.v, yacc[3]);
      pb.u[0] = pk8[2]; pb.u[1] = pk8[3]; pb.u[2] = pk8[6]; pb.u[3] = pk8[7];
      yacc[0] = mfma_bf16(vf1, pb.v, yacc[0]);
      yacc[1] = mfma_bf16(vf3, pb.v, yacc[1]);
      yacc[2] = mfma_bf16(vf5, pb.v, yacc[2]);
      yacc[3] = mfma_bf16(vf7, pb.v, yacc[3]);
    }
    __builtin_amdgcn_s_setprio(0);
    l += lsum;
    // off-chain overflow guard: threshold 2^11.5; fixup AFTER PV (exact)
    float pmax = s[0][0];
    #pragma unroll
    for (int nb=0;nb<4;nb++){
      #pragma unroll
      for (int r=0;r<4;r++) pmax = fmaxf(pmax, s[nb][r]);
    }
    pmax = fmaxf(pmax, __shfl_xor(pmax, 16));
    pmax = fmaxf(pmax, __shfl_xor(pmax, 32));
    if (!__all(pmax <= 2896.31f)){
      float m2n = m2 + __log2f(pmax);
      float al = pmax > 1.f ? 1.f/pmax : 1.f;   // = exp2(m2 - m2n) when pmax>1
      l *= al;
      #pragma unroll
      for (int n=0;n<4;n++) yacc[n] *= al;
      m2 = fmaxf(m2, m2n);
    }
  }

  // per-wave l: sum across the 4 lg-lanes of each q-row
  l += __shfl_xor(l, 16);
  l += __shfl_xor(l, 32);

  // publish partials
  #pragma unroll
  for (int n=0;n<4;n++) yl[wid*4+n][lane] = yacc[n];
  if (lg == 0){ ml[wid][lr] = m2; ll[wid][lr] = l; }
  __syncthreads();

  // merge: wave `wid` produces output slice n = wid
  float m0 = ml[0][lr], m1 = ml[1][lr], m2r = ml[2][lr], m3 = ml[3][lr];
  float ms = fmaxf(fmaxf(m0, m1), fmaxf(m2r, m3));
  float a0 = fexp2(m0 - ms), a1 = fexp2(m1 - ms),
        a2 = fexp2(m2r - ms), a3 = fexp2(m3 - ms);
  float Ls = a0*ll[0][lr] + a1*ll[1][lr] + a2*ll[2][lr] + a3*ll[3][lr];
  f32x4 y0 = yl[0*4+wid][lane], y1 = yl[1*4+wid][lane],
        y2 = yl[2*4+wid][lane], y3 = yl[3*4+wid][lane];
  f32x4 ys;
  #pragma unroll
  for (int r=0;r<4;r++) ys[r] = a0*y0[r] + a1*y1[r] + a2*y2[r] + a3*y3[r];
  float inv = 1.0f / Ls;
  uint2 o;
  o.x = cvtpk_bf16(ys[0]*inv, ys[1]*inv);
  o.y = cvtpk_bf16(ys[2]*inv, ys[3]*inv);
  *(uint2*)&yp[(size_t)(b*2048 + qg)*768 + h*64 + wid*16 + lg*4] = o;
}

extern "C" void kernel_launch(void* const* d_in, const int* in_sizes, int n_in,
                              void* d_out, int out_size, void* d_ws, size_t ws_size,
                              hipStream_t stream)
{
  const float* x  = (const float*)d_in[0];   // [2,2048,768]
  const float* Wa = (const float*)d_in[1];   // [768,2304]
  const float* ba = (const float*)d_in[2];   // [2304]
  const float* Wp = (const float*)d_in[3];   // [768,768]
  const float* bp = (const float*)d_in[4];   // [768]
  float* out = (float*)d_out;                // [2,2048,768] fp32
  char* ws = (char*)d_ws;
  u16* xb  = (u16*)(ws + 0);         // x bf16          [4096][768]
  u16* wt  = (u16*)(ws + 6291456);   // W_attn^T bf16   [2304][768]
  u16* wpt = (u16*)(ws + 9830400);   // W_proj^T bf16   [768][768]
  u16* qb  = (u16*)(ws + 11010048);  // q bf16 (scaled) [24][2048][64]
  u16* kb  = (u16*)(ws + 17301504);  // k bf16          [24][2048][64]
  u16* vtb = (u16*)(ws + 23592960);  // v^T bf16        [24][64][2048]
  u16* yb  = (u16*)(ws + 29884416);  // attn out bf16   [4096][768]

  cast_x_k<<<3072, 256, 0, stream>>>(x, xb, 786432);
  transpose_cast_k<<<dim3(36,12), 256, 0, stream>>>(Wa, wt, 768, 2304);
  transpose_cast_k<<<dim3(12,12), 256, 0, stream>>>(Wp, wpt, 768, 768);
  gemm_bf16_k<<<dim3(18,32), 256, 0, stream>>>(xb, wt, 4096, 2304, 768, ba, 1,
                                               qb, kb, vtb, nullptr);
  attn_k<<<3072, 256, 0, stream>>>(qb, kb, vtb, yb);
  gemm_bf16_k<<<dim3(6,32), 256, 0, stream>>>(yb, wpt, 4096, 768, 768, bp, 0,
                                              nullptr, nullptr, nullptr, out);
}

// Round 9
// 128.864 us; speedup vs baseline: 1.3620x; 1.2737x over previous
//
#include <hip/hip_runtime.h>
#include <stdint.h>

typedef unsigned short u16;
typedef __attribute__((ext_vector_type(8))) short bf16x8;
typedef __attribute__((ext_vector_type(4))) float f32x4;

__device__ __forceinline__ u16 f2bf(float f){
  union { float f; uint32_t u; } v; v.f = f;
  uint32_t u = v.u;
  u += 0x7FFFu + ((u >> 16) & 1u);
  return (u16)(u >> 16);
}

__device__ __forceinline__ float fexp2(float x){
#if __has_builtin(__builtin_amdgcn_exp2f)
  return __builtin_amdgcn_exp2f(x);
#else
  return exp2f(x);
#endif
}

__device__ __forceinline__ uint32_t cvtpk_bf16(float lo, float hi){
  uint32_t d;
  asm("v_cvt_pk_bf16_f32 %0, %1, %2" : "=v"(d) : "v"(lo), "v"(hi));
  return d;
}

__device__ __forceinline__ f32x4 mfma_bf16(bf16x8 a, bf16x8 b, f32x4 c){
  return __builtin_amdgcn_mfma_f32_16x16x32_bf16(a, b, c, 0, 0, 0);
}

// burst load: dwordx4 from SGPR base + 32-bit voffset (+imm). "=&v" early-clobber
// keeps burst results simultaneously live.
#define GLOADX4(dst, off, sbase)                                            \
  asm volatile("global_load_dwordx4 %0, %1, %2"                             \
               : "=&v"(dst) : "v"(off), "s"(sbase))
#define GLOADX4_O64(dst, off, sbase)                                        \
  asm volatile("global_load_dwordx4 %0, %1, %2 offset:64"                   \
               : "=&v"(dst) : "v"(off), "s"(sbase))

// 0.125 (1/sqrt(64)) * log2(e) -- folded into Q at the QKV epilogue
#define QSCALE 0.1803368801111244f

// ---------------- cast x (fp32 -> bf16), 4 elems/thread ----------------
__global__ __launch_bounds__(256) void cast_x_k(const float* __restrict__ x,
                                                u16* __restrict__ xb, int n4){
  int i = blockIdx.x*256 + threadIdx.x;
  if (i >= n4) return;
  float4 v = reinterpret_cast<const float4*>(x)[i];
  uint2 o;
  o.x = (uint32_t)f2bf(v.x) | ((uint32_t)f2bf(v.y) << 16);
  o.y = (uint32_t)f2bf(v.z) | ((uint32_t)f2bf(v.w) << 16);
  reinterpret_cast<uint2*>(xb)[i] = o;
}

// ---------------- transpose+cast: fp32 [R][C] -> bf16 [C][R] ----------------
__global__ __launch_bounds__(256) void transpose_cast_k(const float* __restrict__ in,
                                                        u16* __restrict__ out,
                                                        int R, int C){
  __shared__ u16 tile[64][66];
  int c0 = blockIdx.x*64, r0 = blockIdx.y*64;
  int tc = threadIdx.x & 63, t4 = threadIdx.x >> 6;
  #pragma unroll
  for (int i=0;i<16;i++){ int r = t4 + i*4; tile[r][tc] = f2bf(in[(size_t)(r0+r)*C + c0 + tc]); }
  __syncthreads();
  #pragma unroll
  for (int i=0;i<16;i++){ int cc = t4 + i*4; out[(size_t)(c0+cc)*R + r0 + tc] = tile[tc][cc]; }
}

// ---------------- bf16 MFMA GEMM: C[M][N] = A[M][K] * Bt[N][K]^T + bias ----------------
// (reg-staged; frozen)
#define LDP 40   // padded LDS row stride (shorts)

__global__ __launch_bounds__(256) void gemm_bf16_k(
    const u16* __restrict__ A, const u16* __restrict__ Bt,
    int M, int N, int K, const float* __restrict__ bias, int mode,
    u16* __restrict__ qo, u16* __restrict__ ko, u16* __restrict__ vo,
    float* __restrict__ fo)
{
  __shared__ u16 As[128*LDP];
  __shared__ u16 Bs[128*LDP];
  const int m0 = blockIdx.y*128, n0 = blockIdx.x*128;
  const int tid = threadIdx.x, lane = tid & 63, wid = tid >> 6;
  const int lr = lane & 15, lg = lane >> 4;
  const int wr = wid >> 1, wc = wid & 1;
  f32x4 acc[4][4] = {};
  const int nk = K >> 5;
  for (int kk = 0; kk < nk; ++kk){
    #pragma unroll
    for (int s = 0; s < 2; ++s){
      int ci = tid + 256*s;
      int row = ci >> 2, ch = ci & 3;
      *(uint4*)&As[row*LDP + ch*8] = *(const uint4*)&A[(size_t)(m0+row)*K + kk*32 + ch*8];
      *(uint4*)&Bs[row*LDP + ch*8] = *(const uint4*)&Bt[(size_t)(n0+row)*K + kk*32 + ch*8];
    }
    __syncthreads();
    bf16x8 af[4], bfr[4];
    #pragma unroll
    for (int m=0;m<4;m++) af[m] = *(const bf16x8*)&As[(wr*64 + m*16 + lr)*LDP + lg*8];
    #pragma unroll
    for (int n=0;n<4;n++) bfr[n] = *(const bf16x8*)&Bs[(wc*64 + n*16 + lr)*LDP + lg*8];
    #pragma unroll
    for (int m=0;m<4;m++)
      #pragma unroll
      for (int n=0;n<4;n++)
        acc[m][n] = mfma_bf16(af[m], bfr[n], acc[m][n]);
    __syncthreads();
  }
  if (mode == 0){
    #pragma unroll
    for (int m=0;m<4;m++)
      #pragma unroll
      for (int n=0;n<4;n++){
        int gn = n0 + wc*64 + n*16 + lr;
        float bv = bias[gn];
        #pragma unroll
        for (int r=0;r<4;r++){
          int gm = m0 + wr*64 + m*16 + lg*4 + r;
          fo[(size_t)gm*N + gn] = acc[m][n][r] + bv;
        }
      }
  } else {
    int which = n0 / 768;               // 0=q 1=k 2=v, uniform per block
    u16* dst = (which==0) ? qo : ko;
    float sc = (which==0) ? QSCALE : 1.0f;
    #pragma unroll
    for (int m=0;m<4;m++)
      #pragma unroll
      for (int n=0;n<4;n++){
        int gn = n0 + wc*64 + n*16 + lr;
        float bv = bias[gn];
        int cn = gn - which*768;
        int h = cn >> 6, d = cn & 63;
        int gm0 = m0 + wr*64 + m*16 + lg*4;
        int b = gm0 >> 11, t0 = gm0 & 2047;
        if (which < 2){
          #pragma unroll
          for (int r=0;r<4;r++)
            dst[(size_t)((b*12 + h)*2048 + t0 + r)*64 + d] = f2bf((acc[m][n][r] + bv)*sc);
        } else {
          uint2 o;
          o.x = cvtpk_bf16(acc[m][n][0]+bv, acc[m][n][1]+bv);
          o.y = cvtpk_bf16(acc[m][n][2]+bv, acc[m][n][3]+bv);
          *(uint2*)&vo[((size_t)((b*12 + h)*64 + d))*2048 + t0] = o;
        }
      }
  }
}

// ---------------- causal flash attention: 32 q-rows/wave, split-K, XCD-pinned ------
// R2/R5/R7/R8 all ~100us despite different memory strategies -> cost tracks the
// wave-tile COUNT. This round halves it: each wave's K/V 16-load burst serves TWO
// 16-row q-halves (32 rows). Grid 1536 = 24 heads x 64 q-blocks; head = i%24 keeps
// XCD pinning; qb = 63 - i/24 heavy-first. Wave w handles key-tiles t = w, w+4...
// s->p in-place + per-half sequential pack keeps one s[] live at a time.
// Counted waits: vmcnt(8) after K, vmcnt(0) before PV; sched_barrier after each.
// FIXED shift m2=8; raw-score overflow guard off-chain; rare fixup after PV (exact).
__global__ __launch_bounds__(256) void attn_k(
    const u16* __restrict__ qp, const u16* __restrict__ kp,
    const u16* __restrict__ vtp, u16* __restrict__ yp)
{
  __shared__ f32x4 yl[2][16][64];     // [half][w*4+n][lane]
  __shared__ float ml[2][4][16];
  __shared__ float ll[2][4][16];
  const int i = blockIdx.x;
  const int bh = i % 24;
  const int qb = 63 - (i / 24);             // heavy first, all heads at once
  const int q0 = qb * 32;
  const int q0A = q0, q0B = q0 + 16;
  const int b = bh / 12, h = bh - b*12;
  const size_t base = (size_t)bh * 131072;  // 2048*64
  const int tid = threadIdx.x, lane = tid & 63, wid = tid >> 6;
  const int lr = lane & 15, lg = lane >> 4;
  const int qgA = q0A + lr, qgB = q0B + lr;
  const u16* kbase = kp + base;
  const u16* vbase = vtp + base;

  bf16x8 qfA[2], qfB[2];
  #pragma unroll
  for (int kb=0;kb<2;kb++){
    qfA[kb] = *(const bf16x8*)&qp[base + (size_t)qgA*64 + kb*32 + lg*8];
    qfB[kb] = *(const bf16x8*)&qp[base + (size_t)qgB*64 + kb*32 + lg*8];
  }

  f32x4 yA[4] = {}, yB[4] = {};
  float m2A = 8.f, m2B = 8.f, lA = 0.f, lB = 0.f;
  const int nt = (qb >> 1) + 1;

  // 32-bit byte voffsets for this wave's first tile (t = wid); bumped per iter
  uint32_t ka0, ka1, ka2, ka3, va0, va1, va2, va3;
  {
    int p0 = ((0)*32 + (lr>>2)*8 + (0)*4 + (lr&3))*64 + lg*8;   // nb=0 pi-perm
    int p1 = ((1)*32 + (lr>>2)*8 + (0)*4 + (lr&3))*64 + lg*8;   // nb=1
    int p2 = ((0)*32 + (lr>>2)*8 + (1)*4 + (lr&3))*64 + lg*8;   // nb=2
    int p3 = ((1)*32 + (lr>>2)*8 + (1)*4 + (lr&3))*64 + lg*8;   // nb=3
    ka0 = (uint32_t)(wid*4096 + p0)*2u;  ka1 = (uint32_t)(wid*4096 + p1)*2u;
    ka2 = (uint32_t)(wid*4096 + p2)*2u;  ka3 = (uint32_t)(wid*4096 + p3)*2u;
    va0 = (uint32_t)((0*16+lr)*2048 + lg*8 + wid*64)*2u;
    va1 = (uint32_t)((1*16+lr)*2048 + lg*8 + wid*64)*2u;
    va2 = (uint32_t)((2*16+lr)*2048 + lg*8 + wid*64)*2u;
    va3 = (uint32_t)((3*16+lr)*2048 + lg*8 + wid*64)*2u;
  }

  for (int t = wid; t < nt; t += 4){
    // ---- 16-load asm burst: K (8) then V (8); second halves via offset:64 ----
    bf16x8 kf0,kf1,kf2,kf3,kf4,kf5,kf6,kf7, vf0,vf1,vf2,vf3,vf4,vf5,vf6,vf7;
    GLOADX4    (kf0, ka0, kbase);  GLOADX4_O64(kf1, ka0, kbase);
    GLOADX4    (kf2, ka1, kbase);  GLOADX4_O64(kf3, ka1, kbase);
    GLOADX4    (kf4, ka2, kbase);  GLOADX4_O64(kf5, ka2, kbase);
    GLOADX4    (kf6, ka3, kbase);  GLOADX4_O64(kf7, ka3, kbase);
    GLOADX4    (vf0, va0, vbase);  GLOADX4_O64(vf1, va0, vbase);
    GLOADX4    (vf2, va1, vbase);  GLOADX4_O64(vf3, va1, vbase);
    GLOADX4    (vf4, va2, vbase);  GLOADX4_O64(vf5, va2, vbase);
    GLOADX4    (vf6, va3, vbase);  GLOADX4_O64(vf7, va3, vbase);
    ka0 += 32768u; ka1 += 32768u; ka2 += 32768u; ka3 += 32768u;
    va0 += 512u;   va1 += 512u;   va2 += 512u;   va3 += 512u;

    const int k0 = t*64;
    const int nbmin[4] = {0, 32, 4, 36};

    // ---- wait K only (V keeps flying) ----
    asm volatile("s_waitcnt vmcnt(8)" ::: "memory");
    __builtin_amdgcn_sched_barrier(0);

    uint32_t pkA[8], pkB[8];
    float smA, smB;
    // per-half: QK + mask + exp(in-place) + lsum + pack; returns raw-score max
    auto half_qk = [&](int q0H, int qgH, const bf16x8 (&qfH)[2],
                       float m2H, float &lH, uint32_t (&pkH)[8]) -> float {
      f32x4 s[4] = {};
      __builtin_amdgcn_s_setprio(1);
      if (k0      <= q0H + 15){ s[0]=mfma_bf16(kf0,qfH[0],s[0]); s[0]=mfma_bf16(kf1,qfH[1],s[0]); }
      if (k0 + 32 <= q0H + 15){ s[1]=mfma_bf16(kf2,qfH[0],s[1]); s[1]=mfma_bf16(kf3,qfH[1],s[1]); }
      if (k0 +  4 <= q0H + 15){ s[2]=mfma_bf16(kf4,qfH[0],s[2]); s[2]=mfma_bf16(kf5,qfH[1],s[2]); }
      if (k0 + 36 <= q0H + 15){ s[3]=mfma_bf16(kf6,qfH[0],s[3]); s[3]=mfma_bf16(kf7,qfH[1],s[3]); }
      __builtin_amdgcn_s_setprio(0);
      if (k0 + 63 > q0H){                  // diagonal tile only: causal mask
        #pragma unroll
        for (int nb=0;nb<4;nb++){
          int kb0 = k0 + (nb&1)*32 + ((nb>>1)&1)*4 + lg*8;
          #pragma unroll
          for (int r=0;r<4;r++)
            if (kb0 + r > qgH) s[nb][r] = -1e30f;
        }
      }
      float smax = -1e30f, lsum = 0.f;
      #pragma unroll
      for (int nb=0;nb<4;nb++){
        if (k0 + nbmin[nb] <= q0H + 15){
          #pragma unroll
          for (int r=0;r<4;r++){
            smax = fmaxf(smax, s[nb][r]);
            float p = fexp2(s[nb][r] - m2H);
            s[nb][r] = p;
            lsum += p;
          }
        } else {
          #pragma unroll
          for (int r=0;r<4;r++) s[nb][r] = 0.f;
        }
      }
      lH += lsum;
      #pragma unroll
      for (int nb=0;nb<4;nb++){
        pkH[nb*2]   = cvtpk_bf16(s[nb][0], s[nb][1]);
        pkH[nb*2+1] = cvtpk_bf16(s[nb][2], s[nb][3]);
      }
      return smax;
    };
    smA = half_qk(q0A, qgA, qfA, m2A, lA, pkA);
    smB = half_qk(q0B, qgB, qfB, m2B, lB, pkB);

    // ---- wait V, then PV for both halves (shared vf) ----
    asm volatile("s_waitcnt vmcnt(0)" ::: "memory");
    __builtin_amdgcn_sched_barrier(0);
    __builtin_amdgcn_s_setprio(1);
    {
      union { uint32_t u[4]; bf16x8 v; } pb;
      pb.u[0]=pkA[0]; pb.u[1]=pkA[1]; pb.u[2]=pkA[4]; pb.u[3]=pkA[5];
      yA[0]=mfma_bf16(vf0,pb.v,yA[0]); yA[1]=mfma_bf16(vf2,pb.v,yA[1]);
      yA[2]=mfma_bf16(vf4,pb.v,yA[2]); yA[3]=mfma_bf16(vf6,pb.v,yA[3]);
      pb.u[0]=pkA[2]; pb.u[1]=pkA[3]; pb.u[2]=pkA[6]; pb.u[3]=pkA[7];
      yA[0]=mfma_bf16(vf1,pb.v,yA[0]); yA[1]=mfma_bf16(vf3,pb.v,yA[1]);
      yA[2]=mfma_bf16(vf5,pb.v,yA[2]); yA[3]=mfma_bf16(vf7,pb.v,yA[3]);
      pb.u[0]=pkB[0]; pb.u[1]=pkB[1]; pb.u[2]=pkB[4]; pb.u[3]=pkB[5];
      yB[0]=mfma_bf16(vf0,pb.v,yB[0]); yB[1]=mfma_bf16(vf2,pb.v,yB[1]);
      yB[2]=mfma_bf16(vf4,pb.v,yB[2]); yB[3]=mfma_bf16(vf6,pb.v,yB[3]);
      pb.u[0]=pkB[2]; pb.u[1]=pkB[3]; pb.u[2]=pkB[6]; pb.u[3]=pkB[7];
      yB[0]=mfma_bf16(vf1,pb.v,yB[0]); yB[1]=mfma_bf16(vf3,pb.v,yB[1]);
      yB[2]=mfma_bf16(vf5,pb.v,yB[2]); yB[3]=mfma_bf16(vf7,pb.v,yB[3]);
    }
    __builtin_amdgcn_s_setprio(0);

    // ---- off-chain overflow guard (combined); rare exact fixup after PV ----
    float d = fmaxf(smA - m2A, smB - m2B);
    d = fmaxf(d, __shfl_xor(d, 16));
    d = fmaxf(d, __shfl_xor(d, 32));
    if (!__all(d <= 11.5f)){
      float sAr = fmaxf(smA, __shfl_xor(smA,16)); sAr = fmaxf(sAr, __shfl_xor(sAr,32));
      float sBr = fmaxf(smB, __shfl_xor(smB,16)); sBr = fmaxf(sBr, __shfl_xor(sBr,32));
      float mAn = fmaxf(m2A, sAr), mBn = fmaxf(m2B, sBr);
      float aA = fexp2(m2A - mAn), aB = fexp2(m2B - mBn);
      lA *= aA; lB *= aB;
      #pragma unroll
      for (int n=0;n<4;n++){ yA[n] *= aA; yB[n] *= aB; }
      m2A = mAn; m2B = mBn;
    }
  }

  // per-wave l: sum across the 4 lg-lanes of each q-row
  lA += __shfl_xor(lA, 16);  lA += __shfl_xor(lA, 32);
  lB += __shfl_xor(lB, 16);  lB += __shfl_xor(lB, 32);

  // publish partials
  #pragma unroll
  for (int n=0;n<4;n++){ yl[0][wid*4+n][lane] = yA[n]; yl[1][wid*4+n][lane] = yB[n]; }
  if (lg == 0){
    ml[0][wid][lr] = m2A; ll[0][wid][lr] = lA;
    ml[1][wid][lr] = m2B; ll[1][wid][lr] = lB;
  }
  __syncthreads();

  // merge: wave `wid` produces output slice n = wid for both halves
  #pragma unroll
  for (int hf=0; hf<2; hf++){
    float m0 = ml[hf][0][lr], m1 = ml[hf][1][lr], m2r = ml[hf][2][lr], m3 = ml[hf][3][lr];
    float ms = fmaxf(fmaxf(m0, m1), fmaxf(m2r, m3));
    float a0 = fexp2(m0 - ms), a1 = fexp2(m1 - ms),
          a2 = fexp2(m2r - ms), a3 = fexp2(m3 - ms);
    float Ls = a0*ll[hf][0][lr] + a1*ll[hf][1][lr] + a2*ll[hf][2][lr] + a3*ll[hf][3][lr];
    f32x4 y0 = yl[hf][0*4+wid][lane], y1 = yl[hf][1*4+wid][lane],
          y2 = yl[hf][2*4+wid][lane], y3 = yl[hf][3*4+wid][lane];
    f32x4 ys;
    #pragma unroll
    for (int r=0;r<4;r++) ys[r] = a0*y0[r] + a1*y1[r] + a2*y2[r] + a3*y3[r];
    float inv = 1.0f / Ls;
    uint2 o;
    o.x = cvtpk_bf16(ys[0]*inv, ys[1]*inv);
    o.y = cvtpk_bf16(ys[2]*inv, ys[3]*inv);
    *(uint2*)&yp[(size_t)(b*2048 + q0 + hf*16 + lr)*768 + h*64 + wid*16 + lg*4] = o;
  }
}

extern "C" void kernel_launch(void* const* d_in, const int* in_sizes, int n_in,
                              void* d_out, int out_size, void* d_ws, size_t ws_size,
                              hipStream_t stream)
{
  const float* x  = (const float*)d_in[0];   // [2,2048,768]
  const float* Wa = (const float*)d_in[1];   // [768,2304]
  const float* ba = (const float*)d_in[2];   // [2304]
  const float* Wp = (const float*)d_in[3];   // [768,768]
  const float* bp = (const float*)d_in[4];   // [768]
  float* out = (float*)d_out;                // [2,2048,768] fp32
  char* ws = (char*)d_ws;
  u16* xb  = (u16*)(ws + 0);         // x bf16          [4096][768]
  u16* wt  = (u16*)(ws + 6291456);   // W_attn^T bf16   [2304][768]
  u16* wpt = (u16*)(ws + 9830400);   // W_proj^T bf16   [768][768]
  u16* qb  = (u16*)(ws + 11010048);  // q bf16 (scaled) [24][2048][64]
  u16* kb  = (u16*)(ws + 17301504);  // k bf16          [24][2048][64]
  u16* vtb = (u16*)(ws + 23592960);  // v^T bf16        [24][64][2048]
  u16* yb  = (u16*)(ws + 29884416);  // attn out bf16   [4096][768]

  cast_x_k<<<3072, 256, 0, stream>>>(x, xb, 786432);
  transpose_cast_k<<<dim3(36,12), 256, 0, stream>>>(Wa, wt, 768, 2304);
  transpose_cast_k<<<dim3(12,12), 256, 0, stream>>>(Wp, wpt, 768, 768);
  gemm_bf16_k<<<dim3(18,32), 256, 0, stream>>>(xb, wt, 4096, 2304, 768, ba, 1,
                                               qb, kb, vtb, nullptr);
  attn_k<<<1536, 256, 0, stream>>>(qb, kb, vtb, yb);
  gemm_bf16_k<<<dim3(6,32), 256, 0, stream>>>(yb, wpt, 4096, 768, 768, bp, 0,
                                              nullptr, nullptr, nullptr, out);
}

// Round 10
// 128.569 us; speedup vs baseline: 1.3651x; 1.0023x over previous
//
#include <hip/hip_runtime.h>
#include <stdint.h>

typedef unsigned short u16;
typedef __attribute__((ext_vector_type(8))) short bf16x8;
typedef __attribute__((ext_vector_type(4))) float f32x4;

__device__ __forceinline__ u16 f2bf(float f){
  union { float f; uint32_t u; } v; v.f = f;
  uint32_t u = v.u;
  u += 0x7FFFu + ((u >> 16) & 1u);
  return (u16)(u >> 16);
}

__device__ __forceinline__ float fexp2(float x){
#if __has_builtin(__builtin_amdgcn_exp2f)
  return __builtin_amdgcn_exp2f(x);
#else
  return exp2f(x);
#endif
}

__device__ __forceinline__ uint32_t cvtpk_bf16(float lo, float hi){
  uint32_t d;
  asm("v_cvt_pk_bf16_f32 %0, %1, %2" : "=v"(d) : "v"(lo), "v"(hi));
  return d;
}

__device__ __forceinline__ f32x4 mfma_bf16(bf16x8 a, bf16x8 b, f32x4 c){
  return __builtin_amdgcn_mfma_f32_16x16x32_bf16(a, b, c, 0, 0, 0);
}

// burst load: dwordx4 from SGPR base + 32-bit voffset (+imm). "=&v" early-clobber
// keeps burst results simultaneously live.
#define GLOADX4(dst, off, sbase)                                            \
  asm volatile("global_load_dwordx4 %0, %1, %2"                             \
               : "=&v"(dst) : "v"(off), "s"(sbase))
#define GLOADX4_O64(dst, off, sbase)                                        \
  asm volatile("global_load_dwordx4 %0, %1, %2 offset:64"                   \
               : "=&v"(dst) : "v"(off), "s"(sbase))

// 0.125 (1/sqrt(64)) * log2(e) -- folded into Q at the QKV epilogue
#define QSCALE 0.1803368801111244f

// ---------------- cast x (fp32 -> bf16), 4 elems/thread ----------------
__global__ __launch_bounds__(256) void cast_x_k(const float* __restrict__ x,
                                                u16* __restrict__ xb, int n4){
  int i = blockIdx.x*256 + threadIdx.x;
  if (i >= n4) return;
  float4 v = reinterpret_cast<const float4*>(x)[i];
  uint2 o;
  o.x = (uint32_t)f2bf(v.x) | ((uint32_t)f2bf(v.y) << 16);
  o.y = (uint32_t)f2bf(v.z) | ((uint32_t)f2bf(v.w) << 16);
  reinterpret_cast<uint2*>(xb)[i] = o;
}

// ---------------- transpose+cast: fp32 [R][C] -> bf16 [C][R] ----------------
__global__ __launch_bounds__(256) void transpose_cast_k(const float* __restrict__ in,
                                                        u16* __restrict__ out,
                                                        int R, int C){
  __shared__ u16 tile[64][66];
  int c0 = blockIdx.x*64, r0 = blockIdx.y*64;
  int tc = threadIdx.x & 63, t4 = threadIdx.x >> 6;
  #pragma unroll
  for (int i=0;i<16;i++){ int r = t4 + i*4; tile[r][tc] = f2bf(in[(size_t)(r0+r)*C + c0 + tc]); }
  __syncthreads();
  #pragma unroll
  for (int i=0;i<16;i++){ int cc = t4 + i*4; out[(size_t)(c0+cc)*R + r0 + tc] = tile[tc][cc]; }
}

// ---------------- bf16 MFMA GEMM: C[M][N] = A[M][K] * Bt[N][K]^T + bias ----------------
// (reg-staged; frozen)
#define LDP 40   // padded LDS row stride (shorts)

__global__ __launch_bounds__(256) void gemm_bf16_k(
    const u16* __restrict__ A, const u16* __restrict__ Bt,
    int M, int N, int K, const float* __restrict__ bias, int mode,
    u16* __restrict__ qo, u16* __restrict__ ko, u16* __restrict__ vo,
    float* __restrict__ fo)
{
  __shared__ u16 As[128*LDP];
  __shared__ u16 Bs[128*LDP];
  const int m0 = blockIdx.y*128, n0 = blockIdx.x*128;
  const int tid = threadIdx.x, lane = tid & 63, wid = tid >> 6;
  const int lr = lane & 15, lg = lane >> 4;
  const int wr = wid >> 1, wc = wid & 1;
  f32x4 acc[4][4] = {};
  const int nk = K >> 5;
  for (int kk = 0; kk < nk; ++kk){
    #pragma unroll
    for (int s = 0; s < 2; ++s){
      int ci = tid + 256*s;
      int row = ci >> 2, ch = ci & 3;
      *(uint4*)&As[row*LDP + ch*8] = *(const uint4*)&A[(size_t)(m0+row)*K + kk*32 + ch*8];
      *(uint4*)&Bs[row*LDP + ch*8] = *(const uint4*)&Bt[(size_t)(n0+row)*K + kk*32 + ch*8];
    }
    __syncthreads();
    bf16x8 af[4], bfr[4];
    #pragma unroll
    for (int m=0;m<4;m++) af[m] = *(const bf16x8*)&As[(wr*64 + m*16 + lr)*LDP + lg*8];
    #pragma unroll
    for (int n=0;n<4;n++) bfr[n] = *(const bf16x8*)&Bs[(wc*64 + n*16 + lr)*LDP + lg*8];
    #pragma unroll
    for (int m=0;m<4;m++)
      #pragma unroll
      for (int n=0;n<4;n++)
        acc[m][n] = mfma_bf16(af[m], bfr[n], acc[m][n]);
    __syncthreads();
  }
  if (mode == 0){
    #pragma unroll
    for (int m=0;m<4;m++)
      #pragma unroll
      for (int n=0;n<4;n++){
        int gn = n0 + wc*64 + n*16 + lr;
        float bv = bias[gn];
        #pragma unroll
        for (int r=0;r<4;r++){
          int gm = m0 + wr*64 + m*16 + lg*4 + r;
          fo[(size_t)gm*N + gn] = acc[m][n][r] + bv;
        }
      }
  } else {
    int which = n0 / 768;               // 0=q 1=k 2=v, uniform per block
    u16* dst = (which==0) ? qo : ko;
    float sc = (which==0) ? QSCALE : 1.0f;
    #pragma unroll
    for (int m=0;m<4;m++)
      #pragma unroll
      for (int n=0;n<4;n++){
        int gn = n0 + wc*64 + n*16 + lr;
        float bv = bias[gn];
        int cn = gn - which*768;
        int h = cn >> 6, d = cn & 63;
        int gm0 = m0 + wr*64 + m*16 + lg*4;
        int b = gm0 >> 11, t0 = gm0 & 2047;
        if (which < 2){
          #pragma unroll
          for (int r=0;r<4;r++)
            dst[(size_t)((b*12 + h)*2048 + t0 + r)*64 + d] = f2bf((acc[m][n][r] + bv)*sc);
        } else {
          uint2 o;
          o.x = cvtpk_bf16(acc[m][n][0]+bv, acc[m][n][1]+bv);
          o.y = cvtpk_bf16(acc[m][n][2]+bv, acc[m][n][3]+bv);
          *(uint2*)&vo[((size_t)((b*12 + h)*64 + d))*2048 + t0] = o;
        }
      }
  }
}

// ---------------- causal flash attention: paired q-blocks, all-resident grid --------
// Grid 768 = 24 heads x 32 PAIRS; block handles q-blocks (pr, 63-pr) of 32 rows each
// (complementary pair -> near-uniform block cost; 768 blocks = exactly 3/CU, ALL
// co-resident from t=0 -> no drain tail). head = i%24 keeps XCD pinning.
// Waves 0,1 split-K (stride 2) over q-block pr; waves 2,3 over q-block 63-pr.
// Each wave: 32 q-rows (2 halves) share one 16-load K/V burst per 64-key tile (R9).
// Counted waits: vmcnt(8) after K, vmcnt(0) before PV; sched_barrier after each.
// FIXED shift m2=8; raw-score overflow guard off-chain; rare exact fixup after PV.
__global__ __launch_bounds__(256) void attn_k(
    const u16* __restrict__ qp, const u16* __restrict__ kp,
    const u16* __restrict__ vtp, u16* __restrict__ yp)
{
  __shared__ f32x4 yl[2][2][2][4][64];   // [wg][half][ws][n][lane]
  __shared__ float ml[2][2][2][16];      // [wg][half][ws][row]
  __shared__ float ll[2][2][2][16];
  const int i = blockIdx.x;
  const int bh = i % 24;
  const int pr = i / 24;                    // 0..31
  const int b = bh / 12, h = bh - b*12;
  const size_t base = (size_t)bh * 131072;  // 2048*64
  const int tid = threadIdx.x, lane = tid & 63, wid = tid >> 6;
  const int wg = wid >> 1, ws = wid & 1;    // q-block select / split-K index
  const int qb = (wg == 0) ? (63 - pr) : pr;  // heavy q-block on waves 0,1
  const int q0 = qb * 32;
  const int q0A = q0, q0B = q0 + 16;
  const int lr = lane & 15, lg = lane >> 4;
  const int qgA = q0A + lr, qgB = q0B + lr;
  const u16* kbase = kp + base;
  const u16* vbase = vtp + base;

  bf16x8 qfA[2], qfB[2];
  #pragma unroll
  for (int kb=0;kb<2;kb++){
    qfA[kb] = *(const bf16x8*)&qp[base + (size_t)qgA*64 + kb*32 + lg*8];
    qfB[kb] = *(const bf16x8*)&qp[base + (size_t)qgB*64 + kb*32 + lg*8];
  }

  f32x4 yA[4] = {}, yB[4] = {};
  float m2A = 8.f, m2B = 8.f, lA = 0.f, lB = 0.f;
  const int nt = (qb >> 1) + 1;             // 64-key tiles covering rows < q0+32

  // 32-bit byte voffsets for this wave's first tile (t = ws); bumped 2 tiles/iter
  uint32_t ka0, ka1, ka2, ka3, va0, va1, va2, va3;
  {
    int p0 = ((0)*32 + (lr>>2)*8 + (0)*4 + (lr&3))*64 + lg*8;   // nb=0 pi-perm
    int p1 = ((1)*32 + (lr>>2)*8 + (0)*4 + (lr&3))*64 + lg*8;   // nb=1
    int p2 = ((0)*32 + (lr>>2)*8 + (1)*4 + (lr&3))*64 + lg*8;   // nb=2
    int p3 = ((1)*32 + (lr>>2)*8 + (1)*4 + (lr&3))*64 + lg*8;   // nb=3
    ka0 = (uint32_t)(ws*4096 + p0)*2u;  ka1 = (uint32_t)(ws*4096 + p1)*2u;
    ka2 = (uint32_t)(ws*4096 + p2)*2u;  ka3 = (uint32_t)(ws*4096 + p3)*2u;
    va0 = (uint32_t)((0*16+lr)*2048 + lg*8 + ws*64)*2u;
    va1 = (uint32_t)((1*16+lr)*2048 + lg*8 + ws*64)*2u;
    va2 = (uint32_t)((2*16+lr)*2048 + lg*8 + ws*64)*2u;
    va3 = (uint32_t)((3*16+lr)*2048 + lg*8 + ws*64)*2u;
  }

  for (int t = ws; t < nt; t += 2){
    // ---- 16-load asm burst: K (8) then V (8); second halves via offset:64 ----
    bf16x8 kf0,kf1,kf2,kf3,kf4,kf5,kf6,kf7, vf0,vf1,vf2,vf3,vf4,vf5,vf6,vf7;
    GLOADX4    (kf0, ka0, kbase);  GLOADX4_O64(kf1, ka0, kbase);
    GLOADX4    (kf2, ka1, kbase);  GLOADX4_O64(kf3, ka1, kbase);
    GLOADX4    (kf4, ka2, kbase);  GLOADX4_O64(kf5, ka2, kbase);
    GLOADX4    (kf6, ka3, kbase);  GLOADX4_O64(kf7, ka3, kbase);
    GLOADX4    (vf0, va0, vbase);  GLOADX4_O64(vf1, va0, vbase);
    GLOADX4    (vf2, va1, vbase);  GLOADX4_O64(vf3, va1, vbase);
    GLOADX4    (vf4, va2, vbase);  GLOADX4_O64(vf5, va2, vbase);
    GLOADX4    (vf6, va3, vbase);  GLOADX4_O64(vf7, va3, vbase);
    ka0 += 16384u; ka1 += 16384u; ka2 += 16384u; ka3 += 16384u;
    va0 += 256u;   va1 += 256u;   va2 += 256u;   va3 += 256u;

    const int k0 = t*64;
    const int nbmin[4] = {0, 32, 4, 36};

    // ---- wait K only (V keeps flying) ----
    asm volatile("s_waitcnt vmcnt(8)" ::: "memory");
    __builtin_amdgcn_sched_barrier(0);

    uint32_t pkA[8], pkB[8];
    float smA, smB;
    // per-half: QK + mask + exp(in-place) + lsum + pack; returns raw-score max
    auto half_qk = [&](int q0H, int qgH, const bf16x8 (&qfH)[2],
                       float m2H, float &lH, uint32_t (&pkH)[8]) -> float {
      f32x4 s[4] = {};
      __builtin_amdgcn_s_setprio(1);
      if (k0      <= q0H + 15){ s[0]=mfma_bf16(kf0,qfH[0],s[0]); s[0]=mfma_bf16(kf1,qfH[1],s[0]); }
      if (k0 + 32 <= q0H + 15){ s[1]=mfma_bf16(kf2,qfH[0],s[1]); s[1]=mfma_bf16(kf3,qfH[1],s[1]); }
      if (k0 +  4 <= q0H + 15){ s[2]=mfma_bf16(kf4,qfH[0],s[2]); s[2]=mfma_bf16(kf5,qfH[1],s[2]); }
      if (k0 + 36 <= q0H + 15){ s[3]=mfma_bf16(kf6,qfH[0],s[3]); s[3]=mfma_bf16(kf7,qfH[1],s[3]); }
      __builtin_amdgcn_s_setprio(0);
      if (k0 + 63 > q0H){                  // diagonal tile only: causal mask
        #pragma unroll
        for (int nb=0;nb<4;nb++){
          int kb0 = k0 + (nb&1)*32 + ((nb>>1)&1)*4 + lg*8;
          #pragma unroll
          for (int r=0;r<4;r++)
            if (kb0 + r > qgH) s[nb][r] = -1e30f;
        }
      }
      float smax = -1e30f, lsum = 0.f;
      #pragma unroll
      for (int nb=0;nb<4;nb++){
        if (k0 + nbmin[nb] <= q0H + 15){
          #pragma unroll
          for (int r=0;r<4;r++){
            smax = fmaxf(smax, s[nb][r]);
            float p = fexp2(s[nb][r] - m2H);
            s[nb][r] = p;
            lsum += p;
          }
        } else {
          #pragma unroll
          for (int r=0;r<4;r++) s[nb][r] = 0.f;
        }
      }
      lH += lsum;
      #pragma unroll
      for (int nb=0;nb<4;nb++){
        pkH[nb*2]   = cvtpk_bf16(s[nb][0], s[nb][1]);
        pkH[nb*2+1] = cvtpk_bf16(s[nb][2], s[nb][3]);
      }
      return smax;
    };
    smA = half_qk(q0A, qgA, qfA, m2A, lA, pkA);
    smB = half_qk(q0B, qgB, qfB, m2B, lB, pkB);

    // ---- wait V, then PV for both halves (shared vf) ----
    asm volatile("s_waitcnt vmcnt(0)" ::: "memory");
    __builtin_amdgcn_sched_barrier(0);
    __builtin_amdgcn_s_setprio(1);
    {
      union { uint32_t u[4]; bf16x8 v; } pb;
      pb.u[0]=pkA[0]; pb.u[1]=pkA[1]; pb.u[2]=pkA[4]; pb.u[3]=pkA[5];
      yA[0]=mfma_bf16(vf0,pb.v,yA[0]); yA[1]=mfma_bf16(vf2,pb.v,yA[1]);
      yA[2]=mfma_bf16(vf4,pb.v,yA[2]); yA[3]=mfma_bf16(vf6,pb.v,yA[3]);
      pb.u[0]=pkA[2]; pb.u[1]=pkA[3]; pb.u[2]=pkA[6]; pb.u[3]=pkA[7];
      yA[0]=mfma_bf16(vf1,pb.v,yA[0]); yA[1]=mfma_bf16(vf3,pb.v,yA[1]);
      yA[2]=mfma_bf16(vf5,pb.v,yA[2]); yA[3]=mfma_bf16(vf7,pb.v,yA[3]);
      pb.u[0]=pkB[0]; pb.u[1]=pkB[1]; pb.u[2]=pkB[4]; pb.u[3]=pkB[5];
      yB[0]=mfma_bf16(vf0,pb.v,yB[0]); yB[1]=mfma_bf16(vf2,pb.v,yB[1]);
      yB[2]=mfma_bf16(vf4,pb.v,yB[2]); yB[3]=mfma_bf16(vf6,pb.v,yB[3]);
      pb.u[0]=pkB[2]; pb.u[1]=pkB[3]; pb.u[2]=pkB[6]; pb.u[3]=pkB[7];
      yB[0]=mfma_bf16(vf1,pb.v,yB[0]); yB[1]=mfma_bf16(vf3,pb.v,yB[1]);
      yB[2]=mfma_bf16(vf5,pb.v,yB[2]); yB[3]=mfma_bf16(vf7,pb.v,yB[3]);
    }
    __builtin_amdgcn_s_setprio(0);

    // ---- off-chain overflow guard (combined); rare exact fixup after PV ----
    float d = fmaxf(smA - m2A, smB - m2B);
    d = fmaxf(d, __shfl_xor(d, 16));
    d = fmaxf(d, __shfl_xor(d, 32));
    if (!__all(d <= 11.5f)){
      float sAr = fmaxf(smA, __shfl_xor(smA,16)); sAr = fmaxf(sAr, __shfl_xor(sAr,32));
      float sBr = fmaxf(smB, __shfl_xor(smB,16)); sBr = fmaxf(sBr, __shfl_xor(sBr,32));
      float mAn = fmaxf(m2A, sAr), mBn = fmaxf(m2B, sBr);
      float aA = fexp2(m2A - mAn), aB = fexp2(m2B - mBn);
      lA *= aA; lB *= aB;
      #pragma unroll
      for (int n=0;n<4;n++){ yA[n] *= aA; yB[n] *= aB; }
      m2A = mAn; m2B = mBn;
    }
  }

  // per-wave l: sum across the 4 lg-lanes of each q-row
  lA += __shfl_xor(lA, 16);  lA += __shfl_xor(lA, 32);
  lB += __shfl_xor(lB, 16);  lB += __shfl_xor(lB, 32);

  // publish partials
  #pragma unroll
  for (int n=0;n<4;n++){
    yl[wg][0][ws][n][lane] = yA[n];
    yl[wg][1][ws][n][lane] = yB[n];
  }
  if (lg == 0){
    ml[wg][0][ws][lr] = m2A; ll[wg][0][ws][lr] = lA;
    ml[wg][1][ws][lr] = m2B; ll[wg][1][ws][lr] = lB;
  }
  __syncthreads();

  // merge (2-way): wave (wg,ws) produces half hf = ws of its q-block, all 4 n-slices
  {
    float m0 = ml[wg][ws][0][lr], m1 = ml[wg][ws][1][lr];
    float msx = fmaxf(m0, m1);
    float a0 = fexp2(m0 - msx), a1 = fexp2(m1 - msx);
    float Ls = a0*ll[wg][ws][0][lr] + a1*ll[wg][ws][1][lr];
    float inv = 1.0f / Ls;
    #pragma unroll
    for (int n=0;n<4;n++){
      f32x4 y0 = yl[wg][ws][0][n][lane], y1 = yl[wg][ws][1][n][lane];
      f32x4 ys;
      #pragma unroll
      for (int r=0;r<4;r++) ys[r] = a0*y0[r] + a1*y1[r];
      uint2 o;
      o.x = cvtpk_bf16(ys[0]*inv, ys[1]*inv);
      o.y = cvtpk_bf16(ys[2]*inv, ys[3]*inv);
      *(uint2*)&yp[(size_t)(b*2048 + q0 + ws*16 + lr)*768 + h*64 + n*16 + lg*4] = o;
    }
  }
}

extern "C" void kernel_launch(void* const* d_in, const int* in_sizes, int n_in,
                              void* d_out, int out_size, void* d_ws, size_t ws_size,
                              hipStream_t stream)
{
  const float* x  = (const float*)d_in[0];   // [2,2048,768]
  const float* Wa = (const float*)d_in[1];   // [768,2304]
  const float* ba = (const float*)d_in[2];   // [2304]
  const float* Wp = (const float*)d_in[3];   // [768,768]
  const float* bp = (const float*)d_in[4];   // [768]
  float* out = (float*)d_out;                // [2,2048,768] fp32
  char* ws = (char*)d_ws;
  u16* xb  = (u16*)(ws + 0);         // x bf16          [4096][768]
  u16* wt  = (u16*)(ws + 6291456);   // W_attn^T bf16   [2304][768]
  u16* wpt = (u16*)(ws + 9830400);   // W_proj^T bf16   [768][768]
  u16* qb  = (u16*)(ws + 11010048);  // q bf16 (scaled) [24][2048][64]
  u16* kb  = (u16*)(ws + 17301504);  // k bf16          [24][2048][64]
  u16* vtb = (u16*)(ws + 23592960);  // v^T bf16        [24][64][2048]
  u16* yb  = (u16*)(ws + 29884416);  // attn out bf16   [4096][768]

  cast_x_k<<<3072, 256, 0, stream>>>(x, xb, 786432);
  transpose_cast_k<<<dim3(36,12), 256, 0, stream>>>(Wa, wt, 768, 2304);
  transpose_cast_k<<<dim3(12,12), 256, 0, stream>>>(Wp, wpt, 768, 768);
  gemm_bf16_k<<<dim3(18,32), 256, 0, stream>>>(xb, wt, 4096, 2304, 768, ba, 1,
                                               qb, kb, vtb, nullptr);
  attn_k<<<768, 256, 0, stream>>>(qb, kb, vtb, yb);
  gemm_bf16_k<<<dim3(6,32), 256, 0, stream>>>(yb, wpt, 4096, 768, 768, bp, 0,
                                              nullptr, nullptr, nullptr, out);
}